// Round 12
// baseline (655.652 us; speedup 1.0000x reference)
//
#include <hip/hip_runtime.h>

#define NN 8192
#define NE 262144

typedef short bf16x8 __attribute__((ext_vector_type(8)));
typedef float f32x16 __attribute__((ext_vector_type(16)));
typedef float f32x4 __attribute__((ext_vector_type(4)));

__device__ __forceinline__ unsigned short f2bf(float f) {
  unsigned u = __float_as_uint(f);
  u += 0x7fffu + ((u >> 16) & 1u);
  return (unsigned short)(u >> 16);
}
__device__ __forceinline__ float bflo(unsigned u) { return __uint_as_float(u << 16); }
__device__ __forceinline__ float bfhi(unsigned u) { return __uint_as_float(u & 0xffff0000u); }

// ---- prep: transpose+convert weights, zero counts ----
__global__ void k_prep(const float* __restrict__ W1, const float* __restrict__ W2,
                       unsigned short* __restrict__ W1t, unsigned short* __restrict__ W2t,
                       int* __restrict__ counts) {
  int id = blockIdx.x * blockDim.x + threadIdx.x;
  int stride = gridDim.x * blockDim.x;
  for (int t = id; t < 512 * 256; t += stride) {
    int k = t >> 8, c = t & 255;               // W1[k][c] -> W1t[c][k]
    W1t[c * 512 + k] = f2bf(W1[t]);
  }
  for (int t = id; t < 256 * 128; t += stride) {
    int k = t >> 7, c = t & 127;               // W2[k][c] -> W2t[c][k]
    W2t[c * 256 + k] = f2bf(W2[t]);
  }
  for (int t = id; t < NN; t += stride) counts[t] = 0;
}

// ---- CSR build ----
__global__ void k_hist(const int* __restrict__ rows, int* __restrict__ counts) {
  int id = blockIdx.x * blockDim.x + threadIdx.x;
  if (id < NE) atomicAdd(&counts[rows[id]], 1);
}

__global__ void k_scan(const int* __restrict__ counts, int* __restrict__ starts,
                       int* __restrict__ cursor) {
  __shared__ int sums[1024];
  int t = threadIdx.x;
  int base = t * 8;
  int local[8];
  int s = 0;
  #pragma unroll
  for (int i = 0; i < 8; ++i) { local[i] = s; s += counts[base + i]; }
  sums[t] = s;
  __syncthreads();
  for (int off = 1; off < 1024; off <<= 1) {
    int v = 0;
    if (t >= off) v = sums[t - off];
    __syncthreads();
    sums[t] += v;
    __syncthreads();
  }
  int pre = sums[t] - s;
  #pragma unroll
  for (int i = 0; i < 8; ++i) {
    starts[base + i] = pre + local[i];
    cursor[base + i] = pre + local[i];
  }
  if (t == 1023) starts[NN] = sums[1023];
}

// scatter (val,col) packed as int2 into CSR order
__global__ void k_scatter(const int* __restrict__ rows, const float* __restrict__ vals,
                          const int* __restrict__ cols, int* __restrict__ cursor,
                          int2* __restrict__ ep) {
  int id = blockIdx.x * blockDim.x + threadIdx.x;
  if (id < NE) {
    int pos = atomicAdd(&cursor[rows[id]], 1);
    ep[pos] = make_int2(__float_as_int(vals[id]), cols[id]);
  }
}

// ---- GEMM: C[8192][N](bf16) = A[8192][K] * Bt[N][K]^T (bf16 MFMA) ----
// Tile 128x64, BK=64, 512 threads = 8 waves (4 row x 2 col), wave tile 32x32.
// AF32: A is f32, converted to bf16 during LDS staging.
template <int K, int N, bool AF32>
__global__ __launch_bounds__(512) void k_gemm(const float* __restrict__ Af,
                                              const unsigned short* __restrict__ Ab,
                                              const unsigned short* __restrict__ Bt,
                                              unsigned short* __restrict__ Cb) {
  __shared__ unsigned char As[128 * 64 * 2];   // [128][64] bf16, row=128B, swz ((r&7)<<4)
  __shared__ unsigned char Bs[64 * 64 * 2];
  const int tid = threadIdx.x;
  const int r0 = blockIdx.x * 128, c0 = blockIdx.y * 64;
  const int wid = tid >> 6, lane = tid & 63;
  const int wr = wid >> 1, wc = wid & 1;
  const int lr = lane & 31, lg = lane >> 5;

  f32x16 acc = {};

  for (int kc = 0; kc < K; kc += 64) {
    __syncthreads();
    #pragma unroll
    for (int q = tid; q < 1024; q += 512) {
      int r = q >> 3, s = q & 7;
      if constexpr (AF32) {
        const float* gp = Af + (size_t)(r0 + r) * K + kc + s * 8;
        float4 v0 = *(const float4*)gp;
        float4 v1 = *(const float4*)(gp + 4);
        unsigned a = (unsigned)f2bf(v0.x) | ((unsigned)f2bf(v0.y) << 16);
        unsigned b = (unsigned)f2bf(v0.z) | ((unsigned)f2bf(v0.w) << 16);
        unsigned c = (unsigned)f2bf(v1.x) | ((unsigned)f2bf(v1.y) << 16);
        unsigned d = (unsigned)f2bf(v1.z) | ((unsigned)f2bf(v1.w) << 16);
        *(uint4*)(As + r * 128 + ((s * 16) ^ ((r & 7) << 4))) = make_uint4(a, b, c, d);
      } else {
        float4 v = *(const float4*)(Ab + (size_t)(r0 + r) * K + kc + s * 8);
        *(float4*)(As + r * 128 + ((s * 16) ^ ((r & 7) << 4))) = v;
      }
    }
    if (tid < 512) {
      int r = tid >> 3, s = tid & 7;
      float4 v = *(const float4*)(Bt + (size_t)(c0 + r) * K + kc + s * 8);
      *(float4*)(Bs + r * 128 + ((s * 16) ^ ((r & 7) << 4))) = v;
    }
    __syncthreads();
    #pragma unroll
    for (int ks = 0; ks < 4; ++ks) {
      int brow = wc * 32 + lr;
      bf16x8 bf = *(const bf16x8*)(Bs + brow * 128 + ((ks * 32 + lg * 16) ^ ((brow & 7) << 4)));
      int arow = wr * 32 + lr;
      bf16x8 af = *(const bf16x8*)(As + arow * 128 + ((ks * 32 + lg * 16) ^ ((arow & 7) << 4)));
      acc = __builtin_amdgcn_mfma_f32_32x32x16_bf16(bf, af, acc, 0, 0, 0);
    }
  }
  {
    int row = r0 + wr * 32 + lr;
    #pragma unroll
    for (int g = 0; g < 4; ++g) {
      unsigned lo = (unsigned)f2bf(acc[4 * g + 0]) | ((unsigned)f2bf(acc[4 * g + 1]) << 16);
      unsigned hi = (unsigned)f2bf(acc[4 * g + 2]) | ((unsigned)f2bf(acc[4 * g + 3]) << 16);
      int colc = c0 + wc * 32 + 8 * g + 4 * lg;
      *(uint2*)(Cb + (size_t)row * N + colc) = make_uint2(lo, hi);
    }
  }
}

// ---- SPMM: one wave per row, CSR (packed int2 edges), bf16 gather ----
template <int F>
__global__ __launch_bounds__(256) void k_spmm(const int* __restrict__ starts,
                                              const int2* __restrict__ ep,
                                              const unsigned short* __restrict__ Sb,
                                              float* __restrict__ outF,
                                              unsigned short* __restrict__ outB) {
  constexpr int V = F / 64;
  int gw = (blockIdx.x * blockDim.x + threadIdx.x) >> 6;
  int lane = threadIdx.x & 63;
  if (gw >= NN) return;
  int s = starts[gw], e = starts[gw + 1];
  float acc[V];
  #pragma unroll
  for (int v = 0; v < V; ++v) acc[v] = 0.f;
  for (int j = s; j < e; ++j) {
    int2 ed = ep[j];
    float w = __int_as_float(ed.x);
    int c = ed.y;
    if constexpr (V == 4) {
      uint2 t = *(const uint2*)(Sb + (size_t)c * F + lane * 4);
      acc[0] += w * bflo(t.x); acc[1] += w * bfhi(t.x);
      acc[2] += w * bflo(t.y); acc[3] += w * bfhi(t.y);
    } else {
      unsigned t = *(const unsigned*)(Sb + (size_t)c * F + lane * 2);
      acc[0] += w * bflo(t); acc[1] += w * bfhi(t);
    }
  }
  #pragma unroll
  for (int v = 0; v < V; ++v) acc[v] = fmaxf(acc[v], 0.f);
  if constexpr (V == 4) {
    unsigned lo = (unsigned)f2bf(acc[0]) | ((unsigned)f2bf(acc[1]) << 16);
    unsigned hi = (unsigned)f2bf(acc[2]) | ((unsigned)f2bf(acc[3]) << 16);
    *(uint2*)(outB + (size_t)gw * F + lane * 4) = make_uint2(lo, hi);
  } else {
    unsigned lo = (unsigned)f2bf(acc[0]) | ((unsigned)f2bf(acc[1]) << 16);
    *(unsigned int*)(outB + (size_t)gw * F + lane * 2) = lo;
    if (outF) {
      *(float2*)(outF + (size_t)gw * F + lane * 2) = make_float2(acc[0], acc[1]);
    }
  }
}

// ---- rec = z z^T to two views. Tile 64(i) x 64(j), LDS 32KB -> 5 blocks/CU.
// Grid x = j-tile (adjacent blocks write adjacent 256B of same rows).
__global__ __launch_bounds__(256) void k_rec(const unsigned short* __restrict__ zb,
                                             float* __restrict__ out0,
                                             float* __restrict__ out1) {
  __shared__ unsigned char lds[32768];
  unsigned char* Ai = lds;                 // [64][128] bf16, row=256B, swz ((r&15)<<4)
  unsigned char* Bj = lds + 16384;         // [64][128] bf16
  const int tid = threadIdx.x;
  const int i0 = blockIdx.y * 64, j0 = blockIdx.x * 64;

  for (int q = tid; q < 1024; q += 256) {  // A: 64 rows x 16 slots of 16B
    int r = q >> 4, s = q & 15;
    float4 v = *(const float4*)(zb + (size_t)(i0 + r) * 128 + s * 8);
    *(float4*)(Ai + r * 256 + ((s * 16) ^ ((r & 15) << 4))) = v;
  }
  for (int q = tid; q < 1024; q += 256) {  // B: 64 rows x 16 slots
    int r = q >> 4, s = q & 15;
    float4 v = *(const float4*)(zb + (size_t)(j0 + r) * 128 + s * 8);
    *(float4*)(Bj + r * 256 + ((s * 16) ^ ((r & 15) << 4))) = v;
  }
  __syncthreads();

  const int wid = tid >> 6, lane = tid & 63;
  const int wr = wid >> 1, wc = wid & 1;       // wave tile: 32(i) x 32(j)
  const int lr = lane & 31, lg = lane >> 5;

  f32x16 acc = {};
  #pragma unroll
  for (int ks = 0; ks < 8; ++ks) {
    int arow = wr * 32 + lr;
    bf16x8 af = *(const bf16x8*)(Ai + arow * 256 + ((ks * 32 + lg * 16) ^ ((arow & 15) << 4)));
    int brow = wc * 32 + lr;
    bf16x8 bf = *(const bf16x8*)(Bj + brow * 256 + ((ks * 32 + lg * 16) ^ ((brow & 15) << 4)));
    acc = __builtin_amdgcn_mfma_f32_32x32x16_bf16(bf, af, acc, 0, 0, 0);
  }

  // transpose via LDS: T[64][68] f32 (17.4KB, reuses staging LDS)
  __syncthreads();
  float* T = (float*)lds;
  {
    int row = wr * 32 + lr;                 // i within tile
    #pragma unroll
    for (int q = 0; q < 4; ++q) {           // acc[4q..4q+3] = 4 consecutive j cols
      int col = wc * 32 + 8 * q + 4 * lg;
      f32x4 v = {acc[4 * q + 0], acc[4 * q + 1], acc[4 * q + 2], acc[4 * q + 3]};
      *(f32x4*)(T + row * 68 + col) = v;
    }
  }
  __syncthreads();
  // write out: 4 passes, 16 rows/pass, 16 threads/row -> 256B contiguous per row
  {
    int rr = tid >> 4, cc = (tid & 15) * 4;
    #pragma unroll
    for (int p = 0; p < 4; ++p) {
      int row = p * 16 + rr;
      f32x4 v = *(const f32x4*)(T + row * 68 + cc);
      size_t idx = (size_t)(i0 + row) * NN + (size_t)(j0 + cc);
      *(f32x4*)(out0 + idx) = v;
      *(f32x4*)(out1 + idx) = v;
    }
  }
}

extern "C" void kernel_launch(void* const* d_in, const int* in_sizes, int n_in,
                              void* d_out, int out_size, void* d_ws, size_t ws_size,
                              hipStream_t stream) {
  const float* x     = (const float*)d_in[0];
  const float* W1    = (const float*)d_in[1];
  const float* W2    = (const float*)d_in[2];
  const float* evals = (const float*)d_in[3];
  const int*   erows = (const int*)d_in[4];
  const int*   ecols = (const int*)d_in[5];

  float* out_z   = (float*)d_out;                       // [8192][128]
  float* out_r0  = out_z + (size_t)NN * 128;            // view 0
  float* out_r1  = out_r0 + (size_t)NN * NN;            // view 1

  char* w = (char*)d_ws;
  unsigned short* W1t = (unsigned short*)w;  w += 256 * 512 * 2;
  unsigned short* W2t = (unsigned short*)w;  w += 128 * 256 * 2;
  unsigned short* g1  = (unsigned short*)w;  w += (size_t)NN * 256 * 2;   // x@W1, bf16
  unsigned short* h1  = (unsigned short*)w;  w += (size_t)NN * 256 * 2;   // relu(spmm), bf16
  unsigned short* g2  = (unsigned short*)w;  w += (size_t)NN * 128 * 2;   // h@W2, bf16
  unsigned short* zb  = (unsigned short*)w;  w += (size_t)NN * 128 * 2;   // z, bf16
  int*   counts = (int*)w;                   w += NN * 4;
  int*   starts = (int*)w;                   w += (NN + 8) * 4;
  int*   cursor = (int*)w;                   w += NN * 4;
  int2*  ep     = (int2*)w;                  w += (size_t)NE * 8;

  k_prep<<<256, 256, 0, stream>>>(W1, W2, W1t, W2t, counts);
  k_hist<<<NE / 256, 256, 0, stream>>>(erows, counts);
  k_scan<<<1, 1024, 0, stream>>>(counts, starts, cursor);
  k_scatter<<<NE / 256, 256, 0, stream>>>(erows, evals, ecols, cursor, ep);

  k_gemm<512, 256, true><<<dim3(64, 4), 512, 0, stream>>>(x, nullptr, W1t, g1);
  k_spmm<256><<<NN / 4, 256, 0, stream>>>(starts, ep, g1, nullptr, h1);
  k_gemm<256, 128, false><<<dim3(64, 2), 512, 0, stream>>>(nullptr, h1, W2t, g2);
  k_spmm<128><<<NN / 4, 256, 0, stream>>>(starts, ep, g2, out_z, zb);
  k_rec<<<dim3(128, 128), 256, 0, stream>>>(zb, out_r0, out_r1);
}

// Round 14
// 645.071 us; speedup vs baseline: 1.0164x; 1.0164x over previous
//
#include <hip/hip_runtime.h>

#define NN 8192
#define NE 262144

typedef short bf16x8 __attribute__((ext_vector_type(8)));
typedef float f32x16 __attribute__((ext_vector_type(16)));
typedef float f32x4 __attribute__((ext_vector_type(4)));

__device__ __forceinline__ unsigned short f2bf(float f) {
  unsigned u = __float_as_uint(f);
  u += 0x7fffu + ((u >> 16) & 1u);
  return (unsigned short)(u >> 16);
}
__device__ __forceinline__ float bflo(unsigned u) { return __uint_as_float(u << 16); }
__device__ __forceinline__ float bfhi(unsigned u) { return __uint_as_float(u & 0xffff0000u); }

// ---- prep: transpose+convert weights, zero counts ----
__global__ void k_prep(const float* __restrict__ W1, const float* __restrict__ W2,
                       unsigned short* __restrict__ W1t, unsigned short* __restrict__ W2t,
                       int* __restrict__ counts) {
  int id = blockIdx.x * blockDim.x + threadIdx.x;
  int stride = gridDim.x * blockDim.x;
  for (int t = id; t < 512 * 256; t += stride) {
    int k = t >> 8, c = t & 255;               // W1[k][c] -> W1t[c][k]
    W1t[c * 512 + k] = f2bf(W1[t]);
  }
  for (int t = id; t < 256 * 128; t += stride) {
    int k = t >> 7, c = t & 127;               // W2[k][c] -> W2t[c][k]
    W2t[c * 256 + k] = f2bf(W2[t]);
  }
  for (int t = id; t < NN; t += stride) counts[t] = 0;
}

// ---- CSR build ----
__global__ void k_hist(const int* __restrict__ rows, int* __restrict__ counts) {
  int id = blockIdx.x * blockDim.x + threadIdx.x;
  if (id < NE) atomicAdd(&counts[rows[id]], 1);
}

__global__ void k_scan(const int* __restrict__ counts, int* __restrict__ starts,
                       int* __restrict__ cursor) {
  __shared__ int sums[1024];
  int t = threadIdx.x;
  int base = t * 8;
  int local[8];
  int s = 0;
  #pragma unroll
  for (int i = 0; i < 8; ++i) { local[i] = s; s += counts[base + i]; }
  sums[t] = s;
  __syncthreads();
  for (int off = 1; off < 1024; off <<= 1) {
    int v = 0;
    if (t >= off) v = sums[t - off];
    __syncthreads();
    sums[t] += v;
    __syncthreads();
  }
  int pre = sums[t] - s;
  #pragma unroll
  for (int i = 0; i < 8; ++i) {
    starts[base + i] = pre + local[i];
    cursor[base + i] = pre + local[i];
  }
  if (t == 1023) starts[NN] = sums[1023];
}

// scatter (val,col) packed as int2 into CSR order
__global__ void k_scatter(const int* __restrict__ rows, const float* __restrict__ vals,
                          const int* __restrict__ cols, int* __restrict__ cursor,
                          int2* __restrict__ ep) {
  int id = blockIdx.x * blockDim.x + threadIdx.x;
  if (id < NE) {
    int pos = atomicAdd(&cursor[rows[id]], 1);
    ep[pos] = make_int2(__float_as_int(vals[id]), cols[id]);
  }
}

// ---- GEMM: C[8192][N](bf16) = A[8192][K] * Bt[N][K]^T (bf16 MFMA) ----
// Tile 128x64, BK=64, 512 threads = 8 waves (4 row x 2 col), wave tile 32x32.
template <int K, int N, bool AF32>
__global__ __launch_bounds__(512) void k_gemm(const float* __restrict__ Af,
                                              const unsigned short* __restrict__ Ab,
                                              const unsigned short* __restrict__ Bt,
                                              unsigned short* __restrict__ Cb) {
  __shared__ unsigned char As[128 * 64 * 2];   // [128][64] bf16, row=128B, swz ((r&7)<<4)
  __shared__ unsigned char Bs[64 * 64 * 2];
  const int tid = threadIdx.x;
  const int r0 = blockIdx.x * 128, c0 = blockIdx.y * 64;
  const int wid = tid >> 6, lane = tid & 63;
  const int wr = wid >> 1, wc = wid & 1;
  const int lr = lane & 31, lg = lane >> 5;

  f32x16 acc = {};

  for (int kc = 0; kc < K; kc += 64) {
    __syncthreads();
    #pragma unroll
    for (int q = tid; q < 1024; q += 512) {
      int r = q >> 3, s = q & 7;
      if constexpr (AF32) {
        const float* gp = Af + (size_t)(r0 + r) * K + kc + s * 8;
        float4 v0 = *(const float4*)gp;
        float4 v1 = *(const float4*)(gp + 4);
        unsigned a = (unsigned)f2bf(v0.x) | ((unsigned)f2bf(v0.y) << 16);
        unsigned b = (unsigned)f2bf(v0.z) | ((unsigned)f2bf(v0.w) << 16);
        unsigned c = (unsigned)f2bf(v1.x) | ((unsigned)f2bf(v1.y) << 16);
        unsigned d = (unsigned)f2bf(v1.z) | ((unsigned)f2bf(v1.w) << 16);
        *(uint4*)(As + r * 128 + ((s * 16) ^ ((r & 7) << 4))) = make_uint4(a, b, c, d);
      } else {
        float4 v = *(const float4*)(Ab + (size_t)(r0 + r) * K + kc + s * 8);
        *(float4*)(As + r * 128 + ((s * 16) ^ ((r & 7) << 4))) = v;
      }
    }
    if (tid < 512) {
      int r = tid >> 3, s = tid & 7;
      float4 v = *(const float4*)(Bt + (size_t)(c0 + r) * K + kc + s * 8);
      *(float4*)(Bs + r * 128 + ((s * 16) ^ ((r & 7) << 4))) = v;
    }
    __syncthreads();
    #pragma unroll
    for (int ks = 0; ks < 4; ++ks) {
      int brow = wc * 32 + lr;
      bf16x8 bf = *(const bf16x8*)(Bs + brow * 128 + ((ks * 32 + lg * 16) ^ ((brow & 7) << 4)));
      int arow = wr * 32 + lr;
      bf16x8 af = *(const bf16x8*)(As + arow * 128 + ((ks * 32 + lg * 16) ^ ((arow & 7) << 4)));
      acc = __builtin_amdgcn_mfma_f32_32x32x16_bf16(bf, af, acc, 0, 0, 0);
    }
  }
  {
    int row = r0 + wr * 32 + lr;
    #pragma unroll
    for (int g = 0; g < 4; ++g) {
      unsigned lo = (unsigned)f2bf(acc[4 * g + 0]) | ((unsigned)f2bf(acc[4 * g + 1]) << 16);
      unsigned hi = (unsigned)f2bf(acc[4 * g + 2]) | ((unsigned)f2bf(acc[4 * g + 3]) << 16);
      int colc = c0 + wc * 32 + 8 * g + 4 * lg;
      *(uint2*)(Cb + (size_t)row * N + colc) = make_uint2(lo, hi);
    }
  }
}

// ---- SPMM: one wave per row, CSR (packed int2 edges), bf16 gather ----
template <int F>
__global__ __launch_bounds__(256) void k_spmm(const int* __restrict__ starts,
                                              const int2* __restrict__ ep,
                                              const unsigned short* __restrict__ Sb,
                                              float* __restrict__ outF,
                                              unsigned short* __restrict__ outB) {
  constexpr int V = F / 64;
  int gw = (blockIdx.x * blockDim.x + threadIdx.x) >> 6;
  int lane = threadIdx.x & 63;
  if (gw >= NN) return;
  int s = starts[gw], e = starts[gw + 1];
  float acc[V];
  #pragma unroll
  for (int v = 0; v < V; ++v) acc[v] = 0.f;
  for (int j = s; j < e; ++j) {
    int2 ed = ep[j];
    float w = __int_as_float(ed.x);
    int c = ed.y;
    if constexpr (V == 4) {
      uint2 t = *(const uint2*)(Sb + (size_t)c * F + lane * 4);
      acc[0] += w * bflo(t.x); acc[1] += w * bfhi(t.x);
      acc[2] += w * bflo(t.y); acc[3] += w * bfhi(t.y);
    } else {
      unsigned t = *(const unsigned*)(Sb + (size_t)c * F + lane * 2);
      acc[0] += w * bflo(t); acc[1] += w * bfhi(t);
    }
  }
  #pragma unroll
  for (int v = 0; v < V; ++v) acc[v] = fmaxf(acc[v], 0.f);
  if constexpr (V == 4) {
    unsigned lo = (unsigned)f2bf(acc[0]) | ((unsigned)f2bf(acc[1]) << 16);
    unsigned hi = (unsigned)f2bf(acc[2]) | ((unsigned)f2bf(acc[3]) << 16);
    *(uint2*)(outB + (size_t)gw * F + lane * 4) = make_uint2(lo, hi);
  } else {
    unsigned lo = (unsigned)f2bf(acc[0]) | ((unsigned)f2bf(acc[1]) << 16);
    *(unsigned int*)(outB + (size_t)gw * F + lane * 2) = lo;
    if (outF) {
      *(float2*)(outF + (size_t)gw * F + lane * 2) = make_float2(acc[0], acc[1]);
    }
  }
}

// ---- rec = z z^T to two views. Tile 128(i) x 128(j), 512 thr, 64KB LDS
// (2 blocks/CU). Two-pass LDS-transpose epilogue: 512B contiguous row chunks.
__global__ __launch_bounds__(512) void k_rec(const unsigned short* __restrict__ zb,
                                             float* __restrict__ out0,
                                             float* __restrict__ out1) {
  __shared__ unsigned char lds[65536];
  unsigned char* Ai = lds;                 // [128][256B] bf16, swz ((r&15)<<4)
  unsigned char* Bj = lds + 32768;         // [128][256B]
  const int tid = threadIdx.x;
  const int i0 = blockIdx.y * 128, j0 = blockIdx.x * 128;

  for (int q = tid; q < 2048; q += 512) {  // A: 128 rows x 16 slots of 16B
    int r = q >> 4, s = q & 15;
    float4 v = *(const float4*)(zb + (size_t)(i0 + r) * 128 + s * 8);
    *(float4*)(Ai + r * 256 + ((s * 16) ^ ((r & 15) << 4))) = v;
  }
  for (int q = tid; q < 2048; q += 512) {  // B: 128 rows x 16 slots
    int r = q >> 4, s = q & 15;
    float4 v = *(const float4*)(zb + (size_t)(j0 + r) * 128 + s * 8);
    *(float4*)(Bj + r * 256 + ((s * 16) ^ ((r & 15) << 4))) = v;
  }
  __syncthreads();

  const int wid = tid >> 6, lane = tid & 63;
  const int wr = wid >> 2, wc = wid & 3;   // wave tile: 64(i) x 32(j)
  const int lr = lane & 31, lg = lane >> 5;

  f32x16 acc[2] = {};
  #pragma unroll
  for (int ks = 0; ks < 8; ++ks) {
    int brow = wc * 32 + lr;
    bf16x8 bf = *(const bf16x8*)(Bj + brow * 256 + ((ks * 32 + lg * 16) ^ ((brow & 15) << 4)));
    #pragma unroll
    for (int m = 0; m < 2; ++m) {
      int arow = wr * 64 + m * 32 + lr;
      bf16x8 af = *(const bf16x8*)(Ai + arow * 256 + ((ks * 32 + lg * 16) ^ ((arow & 15) << 4)));
      acc[m] = __builtin_amdgcn_mfma_f32_32x32x16_bf16(bf, af, acc[m], 0, 0, 0);
    }
  }

  // two-pass transpose+store: T[64][132] f32 (33.8KB) reuses staging LDS
  float* T = (float*)lds;
  #pragma unroll
  for (int h = 0; h < 2; ++h) {
    __syncthreads();                       // T region free (staging dead / prev pass stored)
    if (wr == h) {
      #pragma unroll
      for (int m = 0; m < 2; ++m) {
        int row = m * 32 + lr;             // i within this 64-row half
        #pragma unroll
        for (int q = 0; q < 4; ++q) {      // acc[m][4q..4q+3] = 4 consecutive j cols
          int col = wc * 32 + 8 * q + 4 * lg;
          f32x4 v = {acc[m][4 * q + 0], acc[m][4 * q + 1], acc[m][4 * q + 2], acc[m][4 * q + 3]};
          *(f32x4*)(T + row * 132 + col) = v;
        }
      }
    }
    __syncthreads();
    // store 64 rows x 512B: 32 threads/row, 16 rows/iter, 4 iters
    int rr = tid >> 5, cc = (tid & 31) * 4;
    #pragma unroll
    for (int p = 0; p < 4; ++p) {
      int row = p * 16 + rr;
      f32x4 v = *(const f32x4*)(T + row * 132 + cc);
      size_t idx = (size_t)(i0 + h * 64 + row) * NN + (size_t)(j0 + cc);
      *(f32x4*)(out0 + idx) = v;
      *(f32x4*)(out1 + idx) = v;
    }
  }
}

extern "C" void kernel_launch(void* const* d_in, const int* in_sizes, int n_in,
                              void* d_out, int out_size, void* d_ws, size_t ws_size,
                              hipStream_t stream) {
  const float* x     = (const float*)d_in[0];
  const float* W1    = (const float*)d_in[1];
  const float* W2    = (const float*)d_in[2];
  const float* evals = (const float*)d_in[3];
  const int*   erows = (const int*)d_in[4];
  const int*   ecols = (const int*)d_in[5];

  float* out_z   = (float*)d_out;                       // [8192][128]
  float* out_r0  = out_z + (size_t)NN * 128;            // view 0
  float* out_r1  = out_r0 + (size_t)NN * NN;            // view 1

  char* w = (char*)d_ws;
  unsigned short* W1t = (unsigned short*)w;  w += 256 * 512 * 2;
  unsigned short* W2t = (unsigned short*)w;  w += 128 * 256 * 2;
  unsigned short* g1  = (unsigned short*)w;  w += (size_t)NN * 256 * 2;   // x@W1, bf16
  unsigned short* h1  = (unsigned short*)w;  w += (size_t)NN * 256 * 2;   // relu(spmm), bf16
  unsigned short* g2  = (unsigned short*)w;  w += (size_t)NN * 128 * 2;   // h@W2, bf16
  unsigned short* zb  = (unsigned short*)w;  w += (size_t)NN * 128 * 2;   // z, bf16
  int*   counts = (int*)w;                   w += NN * 4;
  int*   starts = (int*)w;                   w += (NN + 8) * 4;
  int*   cursor = (int*)w;                   w += NN * 4;
  int2*  ep     = (int2*)w;                  w += (size_t)NE * 8;

  k_prep<<<256, 256, 0, stream>>>(W1, W2, W1t, W2t, counts);
  k_hist<<<NE / 256, 256, 0, stream>>>(erows, counts);
  k_scan<<<1, 1024, 0, stream>>>(counts, starts, cursor);
  k_scatter<<<NE / 256, 256, 0, stream>>>(erows, evals, ecols, cursor, ep);

  k_gemm<512, 256, true><<<dim3(64, 4), 512, 0, stream>>>(x, nullptr, W1t, g1);
  k_spmm<256><<<NN / 4, 256, 0, stream>>>(starts, ep, g1, nullptr, h1);
  k_gemm<256, 128, false><<<dim3(64, 2), 512, 0, stream>>>(nullptr, h1, W2t, g2);
  k_spmm<128><<<NN / 4, 256, 0, stream>>>(starts, ep, g2, out_z, zb);
  k_rec<<<dim3(64, 64), 512, 0, stream>>>(zb, out_r0, out_r1);
}